// Round 7
// baseline (1456.126 us; speedup 1.0000x reference)
//
#include <hip/hip_runtime.h>

#define EMB 64
#define FB 64                    // rows per fine bucket (LDS accumulate tile)
#define PAD 4                    // LDS row padding (bank-conflict break)
#define CSHIFT 10                // coarse bucket = row >> 10 (1024-node, 64KB windows)
#define EPB 4096                 // edges per block in build_pass1
#define HCHUNK 8192              // edges per block in histo_fine
#define MAXFB 2400               // max fine buckets supported (150016/64 = 2344)

// native clang vector types for nontemporal builtins
typedef float nt_f4 __attribute__((ext_vector_type(4)));
typedef int   nt_i2 __attribute__((ext_vector_type(2)));

// Copy user_emb ++ item_emb into cur buffer AND into acc (d_out).
__global__ void concat_init(const float4* __restrict__ ue,
                            const float4* __restrict__ ie,
                            float4* __restrict__ cur,
                            float4* __restrict__ acc,
                            int n_user4, int n_total4) {
    int i = blockIdx.x * blockDim.x + threadIdx.x;
    if (i >= n_total4) return;
    float4 v = (i < n_user4) ? ue[i] : ie[i - n_user4];
    cur[i] = v;
    acc[i] = v;
}

// Fine-bucket (64-node) histogram, LDS-aggregated.
__global__ void histo_fine(const int* __restrict__ rows,
                           int* __restrict__ counts,
                           int n_edges, int nb) {
    __shared__ int cnt[MAXFB];
    int tid = threadIdx.x;
    for (int i = tid; i < nb; i += 256) cnt[i] = 0;
    __syncthreads();
    int beg = blockIdx.x * HCHUNK;
    int end = min(beg + HCHUNK, n_edges);
    for (int e = beg + tid; e < end; e += 256)
        atomicAdd(&cnt[rows[e] >> 6], 1);
    __syncthreads();
    for (int i = tid; i < nb; i += 256) {
        int c = cnt[i];
        if (c) atomicAdd(&counts[i], c);
    }
}

// Single-block exclusive scan over nb (<= MAXFB) fine-bucket counts.
// Writes bucket_start[0..nb] (exclusive prefix, total at [nb]).
__global__ void scan_fine(const int* __restrict__ counts,
                          int* __restrict__ bucket_start, int nb) {
    __shared__ int s[1024];
    int tid = threadIdx.x;
    int k = (nb + 1023) >> 10;           // elems per thread (<=4)
    int beg = tid * k;
    int end = min(beg + k, nb);
    int loc[4];
    int sum = 0;
    for (int j = beg; j < end; ++j) {
        loc[j - beg] = counts[j];
        sum += loc[j - beg];
    }
    s[tid] = sum;
    __syncthreads();
    for (int d = 1; d < 1024; d <<= 1) {
        int t = (tid >= d) ? s[tid - d] : 0;
        __syncthreads();
        s[tid] += t;
        __syncthreads();
    }
    int excl = s[tid] - sum;
    for (int j = beg; j < end; ++j) {
        bucket_start[j] = excl;
        excl += loc[j - beg];
    }
    if (tid == 1023) bucket_start[nb] = s[1023];
}

// cursor_coarse[b] = bucket_start[min(b*16, nb)]  (16 fine buckets / coarse)
__global__ void init_coarse_cursors(const int* __restrict__ bucket_start,
                                    int* __restrict__ cursor_coarse,
                                    int nb, int nbc) {
    int b = blockIdx.x * blockDim.x + threadIdx.x;
    if (b >= nbc) return;
    cursor_coarse[b] = bucket_start[min(b * 16, nb)];
}

// Pass 1: coarse-bucket append scatter (1024-node windows), LDS-aggregated
// reservations -> each (block,bucket) writes a ~224B contiguous chunk.
// Payload packed: bits 0..17 = col, bits 18..27 = row & 1023.
__global__ void build_pass1(const int* __restrict__ rows,
                            const int* __restrict__ cols,
                            const float* __restrict__ vals,
                            int* __restrict__ cursor_coarse,
                            int2* __restrict__ es_tmp,
                            int n_edges, int nbc) {
    __shared__ int cnt[160];
    __shared__ int base[160];
    int tid = threadIdx.x;
    int beg = blockIdx.x * EPB;
    int end = min(beg + EPB, n_edges);

    if (tid < nbc) cnt[tid] = 0;
    __syncthreads();

    for (int e = beg + tid; e < end; e += 256)
        atomicAdd(&cnt[rows[e] >> CSHIFT], 1);
    __syncthreads();

    if (tid < nbc) {
        int c = cnt[tid];
        base[tid] = c ? atomicAdd(&cursor_coarse[tid], c) : 0;
        cnt[tid] = 0;
    }
    __syncthreads();

    for (int e = beg + tid; e < end; e += 256) {
        int r = rows[e];
        int b = r >> CSHIFT;
        int pos = base[b] + atomicAdd(&cnt[b], 1);
        es_tmp[pos] = make_int2((cols[e] & 0x3FFFF) | ((r & 1023) << 18),
                                __float_as_int(vals[e]));
    }
}

// Pass 2: one block per coarse window. Scatters the window's edges into its
// 16 fine buckets via LDS cursors — every destination line is assembled by
// exactly one CU (write amp ~= 1). Output keeps col + (row & 63).
__global__ void build_pass2(const int2* __restrict__ es_tmp,
                            const int* __restrict__ bucket_start,
                            int2* __restrict__ es, int nb) {
    __shared__ int fc[16];
    int tid = threadIdx.x;
    int f0 = blockIdx.x * 16;
    if (tid < 16) fc[tid] = bucket_start[min(f0 + tid, nb)];
    int ebeg = bucket_start[min(f0, nb)];
    int eend = bucket_start[min(f0 + 16, nb)];
    __syncthreads();
    for (int j = ebeg + tid; j < eend; j += 256) {
        int2 e = es_tmp[j];
        int f = (e.x >> 24) & 15;
        int pos = atomicAdd(&fc[f], 1);
        es[pos] = make_int2(e.x & 0x00FFFFFF, e.y);
    }
}

// SpMM with LDS accumulation: one block per 64-node fine bucket.
// 16 edge-slots x 16 lanes; lane q owns float4 q of the embedding.
// Fused epilogue: acc += y (NT), last layer acc = (acc+y)*0.25, no y store.
__global__ void __launch_bounds__(256)
spmm_lds(const int* __restrict__ bucket_start,
         const int2* __restrict__ es,
         const float* __restrict__ x,
         float* __restrict__ y,
         float* __restrict__ acc,
         int n_nodes, int last) {
    __shared__ float yl[FB * (EMB + PAD)];
    int tid = threadIdx.x;
    for (int i = tid; i < FB * (EMB + PAD); i += 256) yl[i] = 0.f;
    int b = blockIdx.x;
    int ebeg = bucket_start[b];
    int eend = bucket_start[b + 1];
    __syncthreads();

    int sub = tid >> 4;       // edge slot 0..15
    int q   = tid & 15;       // float4 index within embedding
    const nt_i2* esv = (const nt_i2*)es;
    for (int j = ebeg + sub; j < eend; j += 16) {
        nt_i2 e = __builtin_nontemporal_load(&esv[j]);
        int col  = e.x & 0x3FFFF;
        int lrow = (e.x >> 18) & 63;
        float v = __int_as_float(e.y);
        nt_f4 xv = *(const nt_f4*)(x + (size_t)col * EMB + q * 4);
        float* dst = &yl[lrow * (EMB + PAD) + q * 4];
        atomicAdd(dst + 0, v * xv.x);
        atomicAdd(dst + 1, v * xv.y);
        atomicAdd(dst + 2, v * xv.z);
        atomicAdd(dst + 3, v * xv.w);
    }
    __syncthreads();

    // flush: 64 rows x 16 float4 = 1024 float4, 4 per thread, coalesced
    for (int k = 0; k < 4; ++k) {
        int i = tid + k * 256;
        int lr = i >> 4, qq = i & 15;
        int gr = b * FB + lr;
        if (gr >= n_nodes) continue;
        float* src = &yl[lr * (EMB + PAD) + qq * 4];
        nt_f4 a = {src[0], src[1], src[2], src[3]};
        size_t o = (size_t)gr * EMB + qq * 4;
        nt_f4 ac = __builtin_nontemporal_load((const nt_f4*)(acc + o));
        ac += a;
        if (last) {
            ac *= 0.25f;
        } else {
            __builtin_nontemporal_store(a, (nt_f4*)(y + o));
        }
        __builtin_nontemporal_store(ac, (nt_f4*)(acc + o));
    }
}

extern "C" void kernel_launch(void* const* d_in, const int* in_sizes, int n_in,
                              void* d_out, int out_size, void* d_ws, size_t ws_size,
                              hipStream_t stream) {
    const float* ue   = (const float*)d_in[0];
    const float* ie   = (const float*)d_in[1];
    const int*   rows = (const int*)d_in[2];
    const int*   cols = (const int*)d_in[3];
    const float* vals = (const float*)d_in[4];
    float* out = (float*)d_out;

    const int num_users = in_sizes[0] / EMB;
    const int num_items = in_sizes[1] / EMB;
    const int n_nodes   = num_users + num_items;
    const int n_edges   = in_sizes[2];

    // Workspace layout (~86.5 MB):
    //  buf0, buf1 : ping-pong node embeddings (38.4 MB each)
    //               buf1 doubles as es_tmp during the build (9.6 <= 38.4 MB;
    //               build completes before layer-0 spmm writes buf1)
    //  es         : fine-bucket-grouped packed (col|lrow, val) (9.6 MB)
    //  bucket_start : nb+1 ints (fine-bucket CSR offsets; read every layer)
    //  counts     : nb ints (histogram)
    //  cursor_coarse : nbc ints
    const size_t buf_elems = (size_t)n_nodes * EMB;
    float* buf0 = (float*)d_ws;
    float* buf1 = buf0 + buf_elems;
    int2*  es_tmp = (int2*)buf1;
    int2*  es   = (int2*)(buf1 + buf_elems);
    int*   bucket_start  = (int*)(es + n_edges);
    int*   counts        = bucket_start + (MAXFB + 1);
    int*   cursor_coarse = counts + MAXFB;

    const int n_total4 = n_nodes * (EMB / 4);
    const int n_user4  = num_users * (EMB / 4);
    const int nb  = (n_nodes + FB - 1) / FB;          // fine buckets (2344)
    const int nbc = (n_nodes + (1 << CSHIFT) - 1) >> CSHIFT;  // coarse (147)

    // 0) zero the fine histogram
    (void)hipMemsetAsync(counts, 0, (size_t)nb * sizeof(int), stream);

    // 1) concat inputs into cur buffer and accumulator (d_out)
    {
        int threads = 256;
        int blocks  = (n_total4 + threads - 1) / threads;
        concat_init<<<blocks, threads, 0, stream>>>(
            (const float4*)ue, (const float4*)ie,
            (float4*)buf0, (float4*)out, n_user4, n_total4);
    }

    // 2) build fine-bucket-grouped edge list
    {
        histo_fine<<<(n_edges + HCHUNK - 1) / HCHUNK, 256, 0, stream>>>(
            rows, counts, n_edges, nb);
        scan_fine<<<1, 1024, 0, stream>>>(counts, bucket_start, nb);
        init_coarse_cursors<<<1, 256, 0, stream>>>(
            bucket_start, cursor_coarse, nb, nbc);
        build_pass1<<<(n_edges + EPB - 1) / EPB, 256, 0, stream>>>(
            rows, cols, vals, cursor_coarse, es_tmp, n_edges, nbc);
        build_pass2<<<nbc, 256, 0, stream>>>(es_tmp, bucket_start, es, nb);
    }

    // 3) three propagation layers, acc update fused into SpMM epilogue
    float* cur = buf0;
    float* nxt = buf1;
    for (int layer = 0; layer < 3; ++layer) {
        spmm_lds<<<nb, 256, 0, stream>>>(
            bucket_start, es, cur, nxt, out, n_nodes, layer == 2 ? 1 : 0);
        float* t = cur; cur = nxt; nxt = t;
    }
}

// Round 8
// 451.006 us; speedup vs baseline: 3.2286x; 3.2286x over previous
//
#include <hip/hip_runtime.h>

#define EMB 64
#define CSHIFT 10                // coarse bucket = row >> 10 (1024-row windows)
#define CW (1 << CSHIFT)
#define EPB 4096                 // edges per block in build_pass1

// native clang vector types for nontemporal builtins
typedef float nt_f4 __attribute__((ext_vector_type(4)));
typedef int   nt_i2 __attribute__((ext_vector_type(2)));

// Per-row edge counts.
__global__ void histo(const int* __restrict__ rows, int* __restrict__ counts,
                      int n_edges) {
    int e = blockIdx.x * blockDim.x + threadIdx.x;
    if (e < n_edges) atomicAdd(&counts[rows[e]], 1);
}

// --- hierarchical scan: reduce -> scan block sums -> final scan ---

__global__ void scan_reduce(const int* __restrict__ counts,
                            int* __restrict__ block_sums, int n) {
    __shared__ int red[1024];
    int tid = threadIdx.x;
    int i = blockIdx.x * 1024 + tid;
    red[tid] = (i < n) ? counts[i] : 0;
    __syncthreads();
    for (int d = 512; d > 0; d >>= 1) {
        if (tid < d) red[tid] += red[tid + d];
        __syncthreads();
    }
    if (tid == 0) block_sums[blockIdx.x] = red[0];
}

__global__ void scan_blocksums(int* __restrict__ block_sums, int nb) {
    __shared__ int s[1024];
    int tid = threadIdx.x;
    int v = (tid < nb) ? block_sums[tid] : 0;
    s[tid] = v;
    __syncthreads();
    for (int d = 1; d < 1024; d <<= 1) {
        int t = (tid >= d) ? s[tid - d] : 0;
        __syncthreads();
        s[tid] += t;
        __syncthreads();
    }
    if (tid < nb) block_sums[tid] = s[tid] - v;  // exclusive
}

__global__ void scan_final(const int* __restrict__ counts,
                           const int* __restrict__ block_sums,
                           int* __restrict__ row_start, int n) {
    __shared__ int s[1024];
    int tid = threadIdx.x;
    int i = blockIdx.x * 1024 + tid;
    int v = (i < n) ? counts[i] : 0;
    s[tid] = v;
    __syncthreads();
    for (int d = 1; d < 1024; d <<= 1) {
        int t = (tid >= d) ? s[tid - d] : 0;
        __syncthreads();
        s[tid] += t;
        __syncthreads();
    }
    int excl = s[tid] - v + block_sums[blockIdx.x];
    if (i < n) {
        row_start[i] = excl;
        if (i == n - 1) row_start[n] = excl + v;
    }
}

// cursor_coarse[b] = row_start[min(b<<CSHIFT, n_nodes)]
__global__ void init_coarse(const int* __restrict__ row_start,
                            int* __restrict__ cursor_coarse,
                            int n_nodes, int nbc) {
    int b = blockIdx.x * blockDim.x + threadIdx.x;
    if (b >= nbc) return;
    cursor_coarse[b] = row_start[min(b << CSHIFT, n_nodes)];
}

// Pass 1: coarse-bucket append scatter, LDS-aggregated reservations ->
// each (block,bucket) writes a ~224B contiguous chunk (write amp ~1).
// Payload packed: bits 0..17 = col, bits 18..27 = row & 1023.
__global__ void build_pass1(const int* __restrict__ rows,
                            const int* __restrict__ cols,
                            const float* __restrict__ vals,
                            int* __restrict__ cursor_coarse,
                            int2* __restrict__ es_tmp,
                            int n_edges, int nbc) {
    __shared__ int cnt[160];
    __shared__ int base[160];
    int tid = threadIdx.x;
    int beg = blockIdx.x * EPB;
    int end = min(beg + EPB, n_edges);

    if (tid < nbc) cnt[tid] = 0;
    __syncthreads();

    for (int e = beg + tid; e < end; e += 256)
        atomicAdd(&cnt[rows[e] >> CSHIFT], 1);
    __syncthreads();

    if (tid < nbc) {
        int c = cnt[tid];
        base[tid] = c ? atomicAdd(&cursor_coarse[tid], c) : 0;
        cnt[tid] = 0;
    }
    __syncthreads();

    for (int e = beg + tid; e < end; e += 256) {
        int r = rows[e];
        int b = r >> CSHIFT;
        int pos = base[b] + atomicAdd(&cnt[b], 1);
        es_tmp[pos] = make_int2((cols[e] & 0x3FFFF) | ((r & (CW - 1)) << 18),
                                __float_as_int(vals[e]));
    }
}

// Pass 2: one block per coarse window; 1024 per-row LDS cursors initialized
// from row_start. Every destination line of es is assembled by exactly one
// CU -> write amp ~1. Cursor atomics: 1 per edge, random over 1024 addrs.
__global__ void build_pass2(const int2* __restrict__ es_tmp,
                            const int* __restrict__ row_start,
                            int2* __restrict__ es, int n_nodes) {
    __shared__ int fc[CW];
    int tid = threadIdx.x;
    int w0 = blockIdx.x << CSHIFT;
    for (int i = tid; i < CW; i += 256)
        fc[i] = row_start[min(w0 + i, n_nodes)];
    __syncthreads();
    int ebeg = row_start[min(w0, n_nodes)];
    int eend = row_start[min(w0 + CW, n_nodes)];
    for (int j = ebeg + tid; j < eend; j += 256) {
        int2 e = es_tmp[j];
        int lrow = ((unsigned)e.x) >> 18;
        int pos = atomicAdd(&fc[lrow], 1);
        es[pos] = make_int2(e.x & 0x3FFFF, e.y);
    }
}

// Row-parallel CSR SpMM, 16 lanes per row, NT on streaming traffic.
// first=1: gather from (xu,xi) split inputs and epilogue reads x0 from them
// (acc initialized here — concat kernel eliminated).
// last=1: acc = (acc + y) * 0.25, no y store.
__global__ void spmm_csr(const int* __restrict__ row_start,
                         const int2* __restrict__ es,
                         const float* __restrict__ xu,
                         const float* __restrict__ xi,
                         int nu,
                         float* __restrict__ y,
                         float* __restrict__ acc,
                         int n_nodes, int first, int last) {
    int gid = blockIdx.x * blockDim.x + threadIdx.x;
    int r = gid >> 4;
    if (r >= n_nodes) return;
    int q = gid & 15;
    int beg = row_start[r];
    int end = row_start[r + 1];
    const nt_i2* esv = (const nt_i2*)es;
    nt_f4 a = (nt_f4)(0.f);
    for (int j = beg; j < end; ++j) {
        nt_i2 e = __builtin_nontemporal_load(&esv[j]);
        float v = __int_as_float(e.y);
        int c = e.x;
        const float* base = (c < nu) ? (xu + (size_t)c * EMB)
                                     : (xi + (size_t)(c - nu) * EMB);
        nt_f4 xv = *(const nt_f4*)(base + q * 4);
        a += v * xv;
    }
    size_t o = (size_t)r * EMB + q * 4;
    nt_f4 ac;
    if (first) {
        const float* b0 = (r < nu) ? (xu + (size_t)r * EMB)
                                   : (xi + (size_t)(r - nu) * EMB);
        ac = *(const nt_f4*)(b0 + q * 4);
    } else {
        ac = __builtin_nontemporal_load((const nt_f4*)(acc + o));
    }
    ac += a;
    if (last) {
        ac *= 0.25f;
    } else {
        __builtin_nontemporal_store(a, (nt_f4*)(y + o));
    }
    __builtin_nontemporal_store(ac, (nt_f4*)(acc + o));
}

extern "C" void kernel_launch(void* const* d_in, const int* in_sizes, int n_in,
                              void* d_out, int out_size, void* d_ws, size_t ws_size,
                              hipStream_t stream) {
    const float* ue   = (const float*)d_in[0];
    const float* ie   = (const float*)d_in[1];
    const int*   rows = (const int*)d_in[2];
    const int*   cols = (const int*)d_in[3];
    const float* vals = (const float*)d_in[4];
    float* out = (float*)d_out;

    const int num_users = in_sizes[0] / EMB;
    const int num_items = in_sizes[1] / EMB;
    const int n_nodes   = num_users + num_items;
    const int n_edges   = in_sizes[2];

    // Workspace layout (~87.6 MB):
    //  buf0, buf1 : layer outputs (38.4 MB each). buf1 doubles as es_tmp
    //               during the build (9.6 <= 38.4 MB; build completes before
    //               layer-1 spmm writes buf1 — stream-ordered).
    //  es         : row-grouped (col,val) pairs (9.6 MB)
    //  row_start  : n_nodes+1 ints
    //  counts     : n_nodes ints
    //  block_sums : 1024 ints
    //  cursor_coarse : 160 ints
    const size_t buf_elems = (size_t)n_nodes * EMB;
    float* buf0 = (float*)d_ws;
    float* buf1 = buf0 + buf_elems;
    int2*  es_tmp = (int2*)buf1;
    int2*  es   = (int2*)(buf1 + buf_elems);
    int*   row_start     = (int*)(es + n_edges);
    int*   counts        = row_start + (n_nodes + 1);
    int*   block_sums    = counts + n_nodes;
    int*   cursor_coarse = block_sums + 1024;

    const int nb_scan = (n_nodes + 1023) / 1024;            // 147
    const int nbc     = (n_nodes + CW - 1) >> CSHIFT;       // 147

    // 0) zero the histogram
    (void)hipMemsetAsync(counts, 0, (size_t)n_nodes * sizeof(int), stream);

    // 1) build row-grouped edge list: histo -> scan -> coarse append ->
    //    window-local row-exact scatter
    {
        int threads = 256;
        int eblocks = (n_edges + threads - 1) / threads;
        histo<<<eblocks, threads, 0, stream>>>(rows, counts, n_edges);
        scan_reduce<<<nb_scan, 1024, 0, stream>>>(counts, block_sums, n_nodes);
        scan_blocksums<<<1, 1024, 0, stream>>>(block_sums, nb_scan);
        scan_final<<<nb_scan, 1024, 0, stream>>>(counts, block_sums,
                                                 row_start, n_nodes);
        init_coarse<<<1, 256, 0, stream>>>(row_start, cursor_coarse,
                                           n_nodes, nbc);
        build_pass1<<<(n_edges + EPB - 1) / EPB, 256, 0, stream>>>(
            rows, cols, vals, cursor_coarse, es_tmp, n_edges, nbc);
        build_pass2<<<nbc, 256, 0, stream>>>(es_tmp, row_start, es, n_nodes);
    }

    // 2) three propagation layers; layer 0 reads inputs directly and
    //    initializes acc (no concat kernel); acc update fused in epilogue.
    {
        int threads = 256;
        int blocks  = (n_nodes * 16 + threads - 1) / threads;
        // layer 0: x = (ue,ie) split, y -> buf0, acc = x0 + y
        spmm_csr<<<blocks, threads, 0, stream>>>(
            row_start, es, ue, ie, num_users, buf0, out, n_nodes, 1, 0);
        // layer 1: x = buf0, y -> buf1
        spmm_csr<<<blocks, threads, 0, stream>>>(
            row_start, es, buf0, buf0, n_nodes, buf1, out, n_nodes, 0, 0);
        // layer 2: x = buf1, last -> acc = (acc + y) * 0.25
        spmm_csr<<<blocks, threads, 0, stream>>>(
            row_start, es, buf1, buf1, n_nodes, buf0, out, n_nodes, 0, 1);
    }
}